// Round 1
// 525.543 us; speedup vs baseline: 1.2022x; 1.2022x over previous
//
#include <hip/hip_runtime.h>

// SquaredMonarchMatrix on MI355X (gfx950).
// out[r, i2*64+n2] = sum_j2 P1[n2,i2,j2] * y1[r, n2, j2]
// y1[r, i1, n1]    = sum_j1 P0[n1,i1,j1] * x[r, j1*64+n1]
//
// Fused kernel: 8 rows per workgroup, bf16 MFMA 16x16x32, fp32 accumulation.
// LDS = 80 KiB exactly (xs 64 KiB + ys/outs overlay 16 KiB) -> 2 WGs/CU.
// v2: 512-thread blocks (8 waves) -> 16 waves/CU (~47% occupancy) at the same
//     LDS footprint, plus 1-deep prefetch of stage-1 B-fragments to hide L2
//     latency. Same math, same layouts, same swizzles as the 256-thread version.

typedef __bf16 bf16x8 __attribute__((ext_vector_type(8)));
typedef float f32x4 __attribute__((ext_vector_type(4)));

__device__ __forceinline__ unsigned short bf16b(float f) {
  return __builtin_bit_cast(unsigned short, (__bf16)f);
}

// ---------------- param pack kernel ----------------
// Packs P[l][n][i][j] (fp32) into bf16 B-fragment order for mfma_f32_16x16x32_bf16:
// slot g = l<<15 | n<<9 | it<<7 | kb<<6 | lane ; 8 bf16 per slot
// element t: P[l][n][it*16 + (lane&15)][kb*32 + (lane>>4)*8 + t]
__global__ __launch_bounds__(256) void pack_params(const float* __restrict__ p,
                                                   __bf16* __restrict__ wp) {
  unsigned g = blockIdx.x * 256 + threadIdx.x;  // 0..65535
  unsigned lane = g & 63;
  unsigned kb = (g >> 6) & 1;
  unsigned it = (g >> 7) & 3;
  unsigned n  = (g >> 9) & 63;
  unsigned l  = (g >> 15) & 1;
  const float* src = p + (size_t)(((l * 64 + n) * 64 + it * 16 + (lane & 15)) * 64
                                  + kb * 32 + (lane >> 4) * 8);
  f32x4 a = *(const f32x4*)(src);
  f32x4 b = *(const f32x4*)(src + 4);
  bf16x8 o;
  o[0] = (__bf16)a[0]; o[1] = (__bf16)a[1]; o[2] = (__bf16)a[2]; o[3] = (__bf16)a[3];
  o[4] = (__bf16)b[0]; o[5] = (__bf16)b[1]; o[6] = (__bf16)b[2]; o[7] = (__bf16)b[3];
  *(bf16x8*)(wp + (size_t)g * 8) = o;
}

// B-fragment load: packed bf16 path (1 coalesced dwordx4/lane) or fp32 fallback.
__device__ __forceinline__ bf16x8 load_bfrag(const __bf16* __restrict__ wp,
                                             const float* __restrict__ param,
                                             int use_packed,
                                             unsigned l, unsigned n, unsigned it,
                                             unsigned kb, unsigned lane) {
  if (use_packed) {
    size_t idx = ((size_t)((((l * 64 + n) * 4 + it) * 2 + kb) * 64 + lane)) * 8;
    return *(const bf16x8*)(wp + idx);
  } else {
    unsigned mr = lane & 15, quad = lane >> 4;
    const float* s = param + (size_t)(((l * 64 + n) * 64 + it * 16 + mr) * 64
                                      + kb * 32 + quad * 8);
    f32x4 q0 = *(const f32x4*)s;
    f32x4 q1 = *(const f32x4*)(s + 4);
    bf16x8 o;
    o[0] = (__bf16)q0[0]; o[1] = (__bf16)q0[1]; o[2] = (__bf16)q0[2]; o[3] = (__bf16)q0[3];
    o[4] = (__bf16)q1[0]; o[5] = (__bf16)q1[1]; o[6] = (__bf16)q1[2]; o[7] = (__bf16)q1[3];
    return o;
  }
}

// ---------------- main fused kernel ----------------
__global__ __launch_bounds__(512, 4) void monarch_kernel(const float* __restrict__ x,
                                                         const float* __restrict__ param,
                                                         const __bf16* __restrict__ wp,
                                                         int use_packed,
                                                         float* __restrict__ out) {
  // LDS: xs bytes [0,65536): bf16 xs[n=64][r=8][u'=8][jlo=8], swizzle u' = u ^ r ^ ((n>>3)&7)
  //      ys bytes [65536,81920): bf16 ys[i1r=16][r=8][u'=8][t=8], swizzle u' = u ^ r ^ (i1r&7)
  //      outs overlays ys: fp32 outs[r=8][i2h=32][n2s=16], swizzle n2s = n2r ^ (i2&15)
  __shared__ __align__(16) unsigned char smem[81920];
  const unsigned YS = 65536u;

  unsigned tid = threadIdx.x;               // 0..511
  unsigned wave = tid >> 6, lane = tid & 63;  // wave 0..7
  unsigned mr = lane & 15, quad = lane >> 4;
  unsigned rA = mr & 7;  // rows 8..15 duplicate rows 0..7 (Rtile=8)
  unsigned r0 = blockIdx.x * 8;

  // ---- fill xs: coalesced float4 pairs -> bf16 transpose into swizzled layout ----
#pragma unroll 2
  for (int itr = 0; itr < 8; ++itr) {
    unsigned p = itr * 512 + tid;   // pair index 0..4095
    unsigned r = p >> 9;            // 0..7
    unsigned rem = p & 511;
    unsigned jp = rem >> 4;         // 0..31  (j pair: j0=2jp, j0+1)
    unsigned n4r = rem & 15;        // n4 = n4r*4
    unsigned j0 = jp * 2;
    const f32x4* base = (const f32x4*)(x + (size_t)(r0 + r) * 4096);
    f32x4 a = base[j0 * 16 + n4r];
    f32x4 b = base[(j0 + 1) * 16 + n4r];
#pragma unroll
    for (int d = 0; d < 4; ++d) {
      unsigned n = n4r * 4 + d;
      unsigned up = (j0 >> 3) ^ r ^ ((n >> 3) & 7);
      unsigned byte = n * 1024 + r * 128 + up * 16 + (j0 & 7) * 2;
      unsigned v = (unsigned)bf16b(a[d]) | ((unsigned)bf16b(b[d]) << 16);
      *(unsigned*)(smem + byte) = v;
    }
  }
  __syncthreads();

  for (int i1t = 0; i1t < 4; ++i1t) {
    // ---- stage 1: wave w handles n1 in [8w,8w+8), N-tile = i1t ----
    // 1-deep prefetch of B-fragments: hide the L2 hit latency of the packed
    // param loads behind the ds_read + MFMA + ys-write of the current n1.
    unsigned n1b = wave * 8;
    bf16x8 nb0 = load_bfrag(wp, param, use_packed, 0, n1b, i1t, 0, lane);
    bf16x8 nb1 = load_bfrag(wp, param, use_packed, 0, n1b, i1t, 1, lane);
#pragma unroll 2
    for (int t = 0; t < 8; ++t) {
      unsigned n1 = n1b + t;
      bf16x8 b0 = nb0, b1 = nb1;
      if (t < 7) {
        nb0 = load_bfrag(wp, param, use_packed, 0, n1 + 1, i1t, 0, lane);
        nb1 = load_bfrag(wp, param, use_packed, 0, n1 + 1, i1t, 1, lane);
      }
      unsigned c8 = (n1 >> 3) & 7;
      bf16x8 a0 = *(const bf16x8*)(smem + n1 * 1024 + rA * 128 + ((quad ^ rA ^ c8) * 16));
      bf16x8 a1 = *(const bf16x8*)(smem + n1 * 1024 + rA * 128 + (((4 + quad) ^ rA ^ c8) * 16));
      f32x4 acc = {0.f, 0.f, 0.f, 0.f};
      acc = __builtin_amdgcn_mfma_f32_16x16x32_bf16(a0, b0, acc, 0, 0, 0);
      acc = __builtin_amdgcn_mfma_f32_16x16x32_bf16(a1, b1, acc, 0, 0, 0);
      if (quad < 2) {
        unsigned i1r = mr;  // C col = i1 within tile
#pragma unroll
        for (int rg = 0; rg < 4; ++rg) {
          unsigned r = quad * 4 + rg;  // C row
          unsigned upy = (n1 >> 3) ^ r ^ (i1r & 7);
          unsigned byte = YS + i1r * 1024 + r * 128 + upy * 16 + (n1 & 7) * 2;
          *(unsigned short*)(smem + byte) = bf16b(acc[rg]);
        }
      }
    }
    __syncthreads();

    // ---- load & hold stage-2 A fragments (wave w: n2 pass-rel in [2w,2w+2)) ----
    unsigned n2rp = wave * 2;
    bf16x8 A2[2][2];
#pragma unroll
    for (int q2 = 0; q2 < 2; ++q2) {
      unsigned i1r = n2rp + q2;
#pragma unroll
      for (int kb = 0; kb < 2; ++kb) {
        unsigned u = kb * 4 + quad;
        unsigned upy = u ^ rA ^ (i1r & 7);
        A2[q2][kb] = *(const bf16x8*)(smem + YS + i1r * 1024 + rA * 128 + upy * 16);
      }
    }
    __syncthreads();  // ys reads done; outs overlay may be written

    float* outs = (float*)(smem + YS);
#pragma unroll
    for (int h = 0; h < 2; ++h) {
#pragma unroll
      for (int q2 = 0; q2 < 2; ++q2) {
        unsigned n2r = n2rp + q2;
        unsigned n2 = i1t * 16 + n2r;
#pragma unroll
        for (int i2th = 0; i2th < 2; ++i2th) {
          unsigned i2t = h * 2 + i2th;
          bf16x8 b0 = load_bfrag(wp, param, use_packed, 1, n2, i2t, 0, lane);
          bf16x8 b1 = load_bfrag(wp, param, use_packed, 1, n2, i2t, 1, lane);
          f32x4 acc = {0.f, 0.f, 0.f, 0.f};
          acc = __builtin_amdgcn_mfma_f32_16x16x32_bf16(A2[q2][0], b0, acc, 0, 0, 0);
          acc = __builtin_amdgcn_mfma_f32_16x16x32_bf16(A2[q2][1], b1, acc, 0, 0, 0);
          if (quad < 2) {
            unsigned i2 = i2t * 16 + mr;
            unsigned i2h = i2 - h * 32;
            unsigned n2s = n2r ^ (i2 & 15);
#pragma unroll
            for (int rg = 0; rg < 4; ++rg) {
              unsigned r = quad * 4 + rg;
              outs[r * 512 + i2h * 16 + n2s] = acc[rg];
            }
          }
        }
      }
      __syncthreads();
      // flush outs -> global, coalesced (64B runs, permuted within 64-elem blocks)
      for (int k = 0; k < 8; ++k) {
        unsigned L = k * 512 + tid;   // 0..4095
        unsigned r = L >> 9;
        unsigned rem = L & 511;
        unsigned i2h = rem >> 4;
        unsigned n2sp = rem & 15;
        unsigned i2 = h * 32 + i2h;
        unsigned n2 = i1t * 16 + (n2sp ^ (i2 & 15));
        out[(size_t)(r0 + r) * 4096 + i2 * 64 + n2] = outs[L];
      }
      __syncthreads();
    }
  }
}

extern "C" void kernel_launch(void* const* d_in, const int* in_sizes, int n_in,
                              void* d_out, int out_size, void* d_ws, size_t ws_size,
                              hipStream_t stream) {
  const float* x = (const float*)d_in[0];
  const float* param = (const float*)d_in[1];
  float* out = (float*)d_out;

  const size_t PACK_BYTES = (size_t)2 * 64 * 64 * 64 * 2;  // 1 MiB bf16
  int use_packed = (d_ws != nullptr && ws_size >= PACK_BYTES) ? 1 : 0;
  __bf16* wp = (__bf16*)d_ws;

  if (use_packed) {
    pack_params<<<256, 256, 0, stream>>>(param, wp);
  }
  int rows = in_sizes[0] / 4096;   // 16384
  int grid = rows / 8;             // 2048 blocks x 512 threads
  monarch_kernel<<<grid, 512, 0, stream>>>(x, param, wp, use_packed, out);
}